// Round 5
// baseline (201.551 us; speedup 1.0000x reference)
//
#include <hip/hip_runtime.h>
#include <stdint.h>

// ---------------------------------------------------------------------------
// NT-Xent loss, B=8 S=512 D=128  ->  N=4096, 2N=8192 rows, K=128.
// loss = mean_i( -pos_i + log(sum_{j!=i} exp(sim_ij)) ),  sim = z_n z_n^T / T
//
//  k1: normalize rows (fp32), pos in fp32, store z_n*SCALE bf16 where
//      SCALE^2 = log2(e)/T  -> MFMA acc is sim*log2e, exp(sim)=exp2(acc).
//  k2: Gram + exp rowsums. grid (32,32) x 256: block = 256 rows x 256 cols.
//      4 waves x 4 strips of 16 rows; A-frags in registers whole kernel
//      (64 VGPR). B staged per 64-col slab into ONE 16 KB LDS buffer via
//      coalesced uint4 loads -> ds_write_b128 with XOR-swizzled slots
//      (slot = chunk ^ (row&15)) so staging writes AND bfrag ds_read_b128
//      are conflict-free (2-way max = free). Next slab's global loads are
//      prefetched into registers over the current slab's compute. Exact
//      diagonal exclusion (wave-uniform tile check + lane predicate).
//      Exclusive partial row-sums -> partial[32][8192]; no atomics.
//      NOTE: no global_load_lds — R4 showed swizzled per-lane addresses on
//      the async path explode EA traffic (100 MB fetch / 183 MB write).
//  k3: per row sum 32 partials, loss = (sum log - 2*sum pos)/8192.
// No max-subtraction needed: logits in [-14.3,14.3], sums < 1.3e10.
// ---------------------------------------------------------------------------

#define TOTAL   8192
#define NHALF   4096
#define DK      128
#define TEMP_INV 14.285714285714286f
#define SCALE    4.539816f      // sqrt(log2(e)/0.07)
#define JSPLITS 32
#define JCHUNK  256             // cols per block
#define IROWS   256             // rows per block (4 waves x 4 strips x 16)
#define SCOLS   64              // cols per LDS stage
#define NSTAGE  (JCHUNK / SCOLS)  // 4

typedef short  bf16x8  __attribute__((ext_vector_type(8)));
typedef float  floatx4 __attribute__((ext_vector_type(4)));

#if __has_builtin(__builtin_amdgcn_exp2f)
#define EXP2(x) __builtin_amdgcn_exp2f(x)
#else
#define EXP2(x) exp2f(x)
#endif

__device__ __forceinline__ uint32_t f2bf(float f) {
  uint32_t u = __float_as_uint(f);
  return (u + 0x7fffu + ((u >> 16) & 1u)) >> 16;   // RNE; inputs finite
}
__device__ __forceinline__ uint32_t pack2bf(float lo, float hi) {
  return f2bf(lo) | (f2bf(hi) << 16);
}

// --------------------------- kernel 1: normalize ---------------------------
__global__ __launch_bounds__(256) void ntx_norm(
    const float* __restrict__ zi, const float* __restrict__ zj,
    uint32_t* __restrict__ zn,   // packed 2xbf16, [TOTAL][64]
    float* __restrict__ pos,     // [NHALF]
    float* __restrict__ out)     // zero the accumulator target
{
  const int t = threadIdx.x;
  if (blockIdx.x == 0 && t == 0) out[0] = 0.0f;

  const int wave = t >> 6, lane = t & 63;
  const int i = blockIdx.x * 4 + wave;

  const float2 vi = *(const float2*)(zi + (size_t)i * DK + lane * 2);
  const float2 vj = *(const float2*)(zj + (size_t)i * DK + lane * 2);
  float ssi = vi.x * vi.x + vi.y * vi.y;
  float ssj = vj.x * vj.x + vj.y * vj.y;
  float dij = vi.x * vj.x + vi.y * vj.y;
#pragma unroll
  for (int m = 1; m <= 32; m <<= 1) {
    ssi += __shfl_xor(ssi, m, 64);
    ssj += __shfl_xor(ssj, m, 64);
    dij += __shfl_xor(dij, m, 64);
  }
  const float invi = 1.0f / fmaxf(sqrtf(ssi), 1e-12f);
  const float invj = 1.0f / fmaxf(sqrtf(ssj), 1e-12f);

  zn[(size_t)i * 64 + lane] =
      pack2bf(vi.x * invi * SCALE, vi.y * invi * SCALE);
  zn[(size_t)(i + NHALF) * 64 + lane] =
      pack2bf(vj.x * invj * SCALE, vj.y * invj * SCALE);
  if (lane == 0) pos[i] = dij * invi * invj * TEMP_INV;
}

// ---------------- kernel 2: Gram + exp row-sums (LDS staged) ---------------
// grid (32,32) x 256.  Block (bi,bj): rows [bi*256,+256), cols [bj*256,+256)
__global__ __launch_bounds__(256, 4) void ntx_gemm(
    const uint16_t* __restrict__ z,   // [TOTAL][DK] bf16 (scaled)
    float* __restrict__ partial)      // [JSPLITS][TOTAL]
{
  __shared__ uint4 lb4[SCOLS * 16];   // 16 KB: 64 rows x 16 swizzled chunks

  const int t = threadIdx.x;
  const int wave = t >> 6, lane = t & 63;
  const int q = lane >> 4, c = lane & 15;
  const int I0 = blockIdx.x * IROWS;
  const int J0 = blockIdx.y * JCHUNK;
  const int rowbase = I0 + wave * 64;

  // A fragments: 4 strips of 16 rows, 4 k-steps.  A[m=c][k=q*8+j]
  bf16x8 afrag[4][4];
#pragma unroll
  for (int s = 0; s < 4; ++s) {
    const uint16_t* ap = z + (size_t)(rowbase + s * 16 + c) * DK + q * 8;
#pragma unroll
    for (int kk = 0; kk < 4; ++kk)
      afrag[s][kk] = *(const bf16x8*)(ap + kk * 32);
  }

  float runsum[4][4];
#pragma unroll
  for (int s = 0; s < 4; ++s)
#pragma unroll
    for (int r = 0; r < 4; ++r) runsum[s][r] = 0.0f;

  // staging map: linear idx = t + 256*p over (row 0..63, chunk 0..15);
  // per wave-instr: 4 consecutive rows x 16 chunks = 1 KB contiguous global.
  const int srow = t >> 4;        // + 16*p
  const int sch  = t & 15;

  // prefetch slab 0
  uint4 hold[4];
#pragma unroll
  for (int p = 0; p < 4; ++p) {
    const int row = srow + 16 * p;
    hold[p] = *(const uint4*)(z + (size_t)(J0 + row) * DK + sch * 8);
  }

  for (int st = 0; st < NSTAGE; ++st) {
    __syncthreads();              // prior stage's readers done
#pragma unroll
    for (int p = 0; p < 4; ++p) {
      const int row = srow + 16 * p;
      lb4[row * 16 + (sch ^ (row & 15))] = hold[p];   // swizzled store
    }
    __syncthreads();              // slab resident

    if (st < NSTAGE - 1) {        // prefetch next slab over compute
      const int colbase = J0 + (st + 1) * SCOLS;
#pragma unroll
      for (int p = 0; p < 4; ++p) {
        const int row = srow + 16 * p;
        hold[p] = *(const uint4*)(z + (size_t)(colbase + row) * DK + sch * 8);
      }
    }

#pragma unroll
    for (int jt = 0; jt < SCOLS / 16; ++jt) {
      // B[k=q*8+j][n=c]: lds row (jt*16+c), slot (4kk+q) ^ c  (swizzle)
      bf16x8 bfrag[4];
#pragma unroll
      for (int kk = 0; kk < 4; ++kk)
        bfrag[kk] =
            *(const bf16x8*)&lb4[(jt * 16 + c) * 16 + ((4 * kk + q) ^ c)];
      const int jc = J0 + st * SCOLS + jt * 16;      // col = jc + c

#pragma unroll
      for (int s = 0; s < 4; ++s) {
        floatx4 acc = {0.0f, 0.0f, 0.0f, 0.0f};
#pragma unroll
        for (int kk = 0; kk < 4; ++kk)
          acc = __builtin_amdgcn_mfma_f32_16x16x32_bf16(afrag[s][kk],
                                                        bfrag[kk], acc,
                                                        0, 0, 0);
        const int rb = rowbase + s * 16;             // row = rb + q*4 + r
        if (jc == rb) {                              // diagonal 16-tile
#pragma unroll
          for (int r = 0; r < 4; ++r) {
            float e = EXP2(acc[r]);
            runsum[s][r] += (q * 4 + r == c) ? 0.0f : e;
          }
        } else {
#pragma unroll
          for (int r = 0; r < 4; ++r) runsum[s][r] += EXP2(acc[r]);
        }
      }
    }
  }

  // reduce across the 16 c-lanes (cols), write exclusive partial slice
#pragma unroll
  for (int s = 0; s < 4; ++s)
#pragma unroll
    for (int r = 0; r < 4; ++r) {
      float v = runsum[s][r];
      v += __shfl_xor(v, 1, 64);
      v += __shfl_xor(v, 2, 64);
      v += __shfl_xor(v, 4, 64);
      v += __shfl_xor(v, 8, 64);
      runsum[s][r] = v;
    }
  if (c == 0) {
#pragma unroll
    for (int s = 0; s < 4; ++s)
#pragma unroll
      for (int r = 0; r < 4; ++r)
        partial[(size_t)blockIdx.y * TOTAL + rowbase + s * 16 + q * 4 + r] =
            runsum[s][r];
  }
}

// --------------------------- kernel 3: finalize ----------------------------
// grid 32 x 256; one thread per row; one atomicAdd per block into out[0].
__global__ __launch_bounds__(256) void ntx_final(
    const float* __restrict__ partial, const float* __restrict__ pos,
    float* __restrict__ out)
{
  const int r = blockIdx.x * 256 + threadIdx.x;
  float s = 0.0f;
#pragma unroll
  for (int p = 0; p < JSPLITS; ++p) s += partial[(size_t)p * TOTAL + r];
  float acc = __logf(s);
  if (r < NHALF) acc -= 2.0f * pos[r];

#pragma unroll
  for (int m = 1; m <= 32; m <<= 1) acc += __shfl_xor(acc, m, 64);
  __shared__ float red[4];
  const int wave = threadIdx.x >> 6, lane = threadIdx.x & 63;
  if (lane == 0) red[wave] = acc;
  __syncthreads();
  if (threadIdx.x == 0) {
    float b = red[0] + red[1] + red[2] + red[3];
    atomicAdd(out, b * (1.0f / (float)TOTAL));
  }
}

// ---------------------------------------------------------------------------
extern "C" void kernel_launch(void* const* d_in, const int* in_sizes, int n_in,
                              void* d_out, int out_size, void* d_ws,
                              size_t ws_size, hipStream_t stream) {
  const float* zi = (const float*)d_in[0];
  const float* zj = (const float*)d_in[1];
  float* out = (float*)d_out;

  char* ws = (char*)d_ws;
  uint16_t* zn      = (uint16_t*)ws;                                   // 2 MB
  float*    partial = (float*)(ws + (size_t)TOTAL * DK * 2);           // 1 MB
  float*    pos     = (float*)(ws + (size_t)TOTAL * DK * 2 +
                               (size_t)JSPLITS * TOTAL * 4);           // 16 KB

  ntx_norm<<<dim3(NHALF / 4), dim3(256), 0, stream>>>(zi, zj, (uint32_t*)zn,
                                                      pos, out);
  ntx_gemm<<<dim3(TOTAL / IROWS, TOTAL / JCHUNK), dim3(256), 0, stream>>>(
      zn, partial);
  ntx_final<<<dim3(TOTAL / 256), dim3(256), 0, stream>>>(partial, pos, out);
}

// Round 6
// 101.167 us; speedup vs baseline: 1.9923x; 1.9923x over previous
//
#include <hip/hip_runtime.h>
#include <stdint.h>

// ---------------------------------------------------------------------------
// NT-Xent loss, B=8 S=512 D=128  ->  N=4096, 2N=8192 rows, K=128.
// loss = mean_i( -pos_i + log(sum_{j!=i} exp(sim_ij)) ),  sim = z_n z_n^T / T
//
//  k1: normalize rows (fp32), pos in fp32, store z_n*SCALE bf16 where
//      SCALE^2 = log2(e)/T  -> MFMA acc is sim*log2e, exp(sim)=exp2(acc).
//  k2: Gram + exp rowsums. grid (64,16) = 1024 blocks = 4/CU. Block =
//      128 rows x 512 cols; 4 waves x 2 strips of 16 rows. afrag[2][4] =
//      32 VGPR (whole kernel). B: 64-col slabs, LDS DOUBLE buffer (2x16KB),
//      one barrier/stage; global prefetch into hold[4] issued before
//      compute. XOR-swizzled LDS slots (slot = chunk ^ (row&15)): staging
//      ds_write_b128 and bfrag ds_read_b128 both conflict-free (R5: 0
//      conflicts measured). Exact diagonal exclusion. Exclusive partial
//      row-sums -> partial[16][8192]; no atomics.
//      Register budget ~95 < 128 cap @ (256,4): R5's spill trap avoided.
//      (R4 lesson: no global_load_lds with swizzled addresses; R3 lesson:
//      no raw-global B reads.)
//  k3: per row sum 16 partials, loss = (sum log - 2*sum pos)/8192.
// No max-subtraction needed: logits in [-14.3,14.3], sums < 1.3e10.
// ---------------------------------------------------------------------------

#define TOTAL   8192
#define NHALF   4096
#define DK      128
#define TEMP_INV 14.285714285714286f
#define SCALE    4.539816f      // sqrt(log2(e)/0.07)
#define JSPLITS 16
#define JCHUNK  512             // cols per block
#define IROWS   128             // rows per block (4 waves x 2 strips x 16)
#define SCOLS   64              // cols per LDS stage
#define NSTAGE  (JCHUNK / SCOLS)  // 8

typedef short  bf16x8  __attribute__((ext_vector_type(8)));
typedef float  floatx4 __attribute__((ext_vector_type(4)));

#if __has_builtin(__builtin_amdgcn_exp2f)
#define EXP2(x) __builtin_amdgcn_exp2f(x)
#else
#define EXP2(x) exp2f(x)
#endif

__device__ __forceinline__ uint32_t f2bf(float f) {
  uint32_t u = __float_as_uint(f);
  return (u + 0x7fffu + ((u >> 16) & 1u)) >> 16;   // RNE; inputs finite
}
__device__ __forceinline__ uint32_t pack2bf(float lo, float hi) {
  return f2bf(lo) | (f2bf(hi) << 16);
}

// --------------------------- kernel 1: normalize ---------------------------
__global__ __launch_bounds__(256) void ntx_norm(
    const float* __restrict__ zi, const float* __restrict__ zj,
    uint32_t* __restrict__ zn,   // packed 2xbf16, [TOTAL][64]
    float* __restrict__ pos,     // [NHALF]
    float* __restrict__ out)     // zero the accumulator target
{
  const int t = threadIdx.x;
  if (blockIdx.x == 0 && t == 0) out[0] = 0.0f;

  const int wave = t >> 6, lane = t & 63;
  const int i = blockIdx.x * 4 + wave;

  const float2 vi = *(const float2*)(zi + (size_t)i * DK + lane * 2);
  const float2 vj = *(const float2*)(zj + (size_t)i * DK + lane * 2);
  float ssi = vi.x * vi.x + vi.y * vi.y;
  float ssj = vj.x * vj.x + vj.y * vj.y;
  float dij = vi.x * vj.x + vi.y * vj.y;
#pragma unroll
  for (int m = 1; m <= 32; m <<= 1) {
    ssi += __shfl_xor(ssi, m, 64);
    ssj += __shfl_xor(ssj, m, 64);
    dij += __shfl_xor(dij, m, 64);
  }
  const float invi = 1.0f / fmaxf(sqrtf(ssi), 1e-12f);
  const float invj = 1.0f / fmaxf(sqrtf(ssj), 1e-12f);

  zn[(size_t)i * 64 + lane] =
      pack2bf(vi.x * invi * SCALE, vi.y * invi * SCALE);
  zn[(size_t)(i + NHALF) * 64 + lane] =
      pack2bf(vj.x * invj * SCALE, vj.y * invj * SCALE);
  if (lane == 0) pos[i] = dij * invi * invj * TEMP_INV;
}

// ---------- kernel 2: Gram + exp row-sums (LDS dbuf, low-VGPR) -------------
// grid (64,16) x 256.  Block (bi,bj): rows [bi*128,+128), cols [bj*512,+512)
__global__ __launch_bounds__(256, 4) void ntx_gemm(
    const uint16_t* __restrict__ z,   // [TOTAL][DK] bf16 (scaled)
    float* __restrict__ partial)      // [JSPLITS][TOTAL]
{
  __shared__ uint4 lb4[2 * SCOLS * 16];   // 32 KB, two swizzled slabs

  const int t = threadIdx.x;
  const int wave = t >> 6, lane = t & 63;
  const int q = lane >> 4, c = lane & 15;
  const int I0 = blockIdx.x * IROWS;
  const int J0 = blockIdx.y * JCHUNK;
  const int rowbase = I0 + wave * 32;

  // A fragments: 2 strips of 16 rows, 4 k-steps.  A[m=c][k=q*8+j]
  bf16x8 afrag[2][4];
#pragma unroll
  for (int s = 0; s < 2; ++s) {
    const uint16_t* ap = z + (size_t)(rowbase + s * 16 + c) * DK + q * 8;
#pragma unroll
    for (int kk = 0; kk < 4; ++kk)
      afrag[s][kk] = *(const bf16x8*)(ap + kk * 32);
  }

  float runsum[2][4] = {{0.f, 0.f, 0.f, 0.f}, {0.f, 0.f, 0.f, 0.f}};

  // staging map: thread t covers slab-row srow(+16p), 16B chunk sch.
  const int srow = t >> 4;
  const int sch  = t & 15;

  uint4 hold[4];
  // prologue: slab 0 -> buffer 0
#pragma unroll
  for (int p = 0; p < 4; ++p) {
    const int row = srow + 16 * p;
    hold[p] = *(const uint4*)(z + (size_t)(J0 + row) * DK + sch * 8);
  }
#pragma unroll
  for (int p = 0; p < 4; ++p) {
    const int row = srow + 16 * p;
    lb4[row * 16 + (sch ^ (row & 15))] = hold[p];
  }
  __syncthreads();

#pragma unroll 2
  for (int st = 0; st < NSTAGE; ++st) {
    // prefetch next slab (flies over this stage's compute)
    if (st + 1 < NSTAGE) {
      const int colbase = J0 + (st + 1) * SCOLS;
#pragma unroll
      for (int p = 0; p < 4; ++p) {
        const int row = srow + 16 * p;
        hold[p] = *(const uint4*)(z + (size_t)(colbase + row) * DK + sch * 8);
      }
    }

    const uint4* buf = &lb4[(st & 1) * 1024];
#pragma unroll
    for (int jt = 0; jt < SCOLS / 16; ++jt) {
      // B[k=q*8+j][n=c]: lds row (jt*16+c), slot (4kk+q)^c  (swizzled)
      bf16x8 bfrag[4];
#pragma unroll
      for (int kk = 0; kk < 4; ++kk)
        bfrag[kk] =
            *(const bf16x8*)&buf[(jt * 16 + c) * 16 + ((4 * kk + q) ^ c)];
      const int jc = J0 + st * SCOLS + jt * 16;      // col = jc + c

#pragma unroll
      for (int s = 0; s < 2; ++s) {
        floatx4 acc = {0.0f, 0.0f, 0.0f, 0.0f};
#pragma unroll
        for (int kk = 0; kk < 4; ++kk)
          acc = __builtin_amdgcn_mfma_f32_16x16x32_bf16(afrag[s][kk],
                                                        bfrag[kk], acc,
                                                        0, 0, 0);
        const int rb = rowbase + s * 16;             // row = rb + q*4 + r
        if (jc == rb) {                              // diagonal 16-tile
#pragma unroll
          for (int r = 0; r < 4; ++r) {
            float e = EXP2(acc[r]);
            runsum[s][r] += (q * 4 + r == c) ? 0.0f : e;
          }
        } else {
#pragma unroll
          for (int r = 0; r < 4; ++r) runsum[s][r] += EXP2(acc[r]);
        }
      }
    }

    // write next slab into the other buffer; one barrier per stage
    if (st + 1 < NSTAGE) {
      uint4* nbuf = &lb4[((st + 1) & 1) * 1024];
#pragma unroll
      for (int p = 0; p < 4; ++p) {
        const int row = srow + 16 * p;
        nbuf[row * 16 + (sch ^ (row & 15))] = hold[p];
      }
      __syncthreads();
    }
  }

  // reduce across the 16 c-lanes (cols), write exclusive partial slice
#pragma unroll
  for (int s = 0; s < 2; ++s)
#pragma unroll
    for (int r = 0; r < 4; ++r) {
      float v = runsum[s][r];
      v += __shfl_xor(v, 1, 64);
      v += __shfl_xor(v, 2, 64);
      v += __shfl_xor(v, 4, 64);
      v += __shfl_xor(v, 8, 64);
      runsum[s][r] = v;
    }
  if (c == 0) {
#pragma unroll
    for (int s = 0; s < 2; ++s)
#pragma unroll
      for (int r = 0; r < 4; ++r)
        partial[(size_t)blockIdx.y * TOTAL + rowbase + s * 16 + q * 4 + r] =
            runsum[s][r];
  }
}

// --------------------------- kernel 3: finalize ----------------------------
// grid 32 x 256; one thread per row; one atomicAdd per block into out[0].
__global__ __launch_bounds__(256) void ntx_final(
    const float* __restrict__ partial, const float* __restrict__ pos,
    float* __restrict__ out)
{
  const int r = blockIdx.x * 256 + threadIdx.x;
  float s = 0.0f;
#pragma unroll
  for (int p = 0; p < JSPLITS; ++p) s += partial[(size_t)p * TOTAL + r];
  float acc = __logf(s);
  if (r < NHALF) acc -= 2.0f * pos[r];

#pragma unroll
  for (int m = 1; m <= 32; m <<= 1) acc += __shfl_xor(acc, m, 64);
  __shared__ float red[4];
  const int wave = threadIdx.x >> 6, lane = threadIdx.x & 63;
  if (lane == 0) red[wave] = acc;
  __syncthreads();
  if (threadIdx.x == 0) {
    float b = red[0] + red[1] + red[2] + red[3];
    atomicAdd(out, b * (1.0f / (float)TOTAL));
  }
}

// ---------------------------------------------------------------------------
extern "C" void kernel_launch(void* const* d_in, const int* in_sizes, int n_in,
                              void* d_out, int out_size, void* d_ws,
                              size_t ws_size, hipStream_t stream) {
  const float* zi = (const float*)d_in[0];
  const float* zj = (const float*)d_in[1];
  float* out = (float*)d_out;

  char* ws = (char*)d_ws;
  uint16_t* zn      = (uint16_t*)ws;                                   // 2 MB
  float*    partial = (float*)(ws + (size_t)TOTAL * DK * 2);           // 512 KB
  float*    pos     = (float*)(ws + (size_t)TOTAL * DK * 2 +
                               (size_t)JSPLITS * TOTAL * 4);           // 16 KB

  ntx_norm<<<dim3(NHALF / 4), dim3(256), 0, stream>>>(zi, zj, (uint32_t*)zn,
                                                      pos, out);
  ntx_gemm<<<dim3(TOTAL / IROWS, JSPLITS), dim3(256), 0, stream>>>(zn, partial);
  ntx_final<<<dim3(TOTAL / 256), dim3(256), 0, stream>>>(partial, pos, out);
}